// Round 13
// baseline (455.128 us; speedup 1.0000x reference)
//
#include <hip/hip_runtime.h>
#include <hip/hip_bf16.h>

typedef __hip_bfloat16 bf16;
typedef __hip_bfloat162 bf162;

#define N_AUTHOR 20000
#define N_PAPER  40000
#define NEDGE    400000
#define HID      128
#define HEADS    8
#define DIMH     16
#define NCLS     16

typedef short short4v __attribute__((ext_vector_type(4)));
typedef short short8v __attribute__((ext_vector_type(8)));
typedef float f32x4   __attribute__((ext_vector_type(4)));

__device__ __forceinline__ bf162 mk2(float a, float b){
    bf162 r; r.x = __float2bfloat16(a); r.y = __float2bfloat16(b); return r;
}
__device__ __forceinline__ float b2f(short s){
    return __uint_as_float(((unsigned)(unsigned short)s) << 16);
}
__device__ __forceinline__ short f2bs(float v){
    unsigned u = __float_as_uint(v);
    unsigned r = (u + 0x7FFFu + ((u >> 16) & 1u)) >> 16;
    return (short)r;
}
__device__ __forceinline__ float fastrcp(float x){ return __builtin_amdgcn_rcpf(x); }

__device__ __forceinline__ float fast_tanh(float x){
    x = fminf(fmaxf(x, -15.f), 15.f);
    float e = __expf(2.f * x);
    return 1.f - 2.f * fastrcp(e + 1.f);
}

// ---------------------------------------------------------------------------
// LDS-free bf16 MFMA GEMM body, kc-outer (8 B-loads in flight per round).
// ---------------------------------------------------------------------------
template<int KDIM, int EPI>
__device__ __forceinline__ void bgemm_body(
    const bf16* __restrict__ A, const bf16* __restrict__ Wt, const float* __restrict__ Bb,
    bf16* __restrict__ C, const float* __restrict__ qv, float* __restrict__ score,
    int M, int brow, float* red)
{
    const int tid  = threadIdx.x;
    const int lane = tid & 63;
    const int wv   = tid >> 6;
    const int lr   = lane & 15;
    const int quad = lane >> 4;
    const int row0 = brow * 64 + wv * 16;
    const int arow_i = row0 + lr;
    const bool rowok = arow_i < M;
    const bf16* arow = A + (long)arow_i * KDIM;

    short8v afrag[KDIM / 32];
    #pragma unroll
    for (int kc = 0; kc < KDIM / 32; kc++) {
        short8v f = {0,0,0,0,0,0,0,0};
        if (rowok) f = *(const short8v*)(arow + kc * 32 + quad * 8);
        afrag[kc] = f;
    }

    f32x4 acc[8];
    #pragma unroll
    for (int ct = 0; ct < 8; ct++) acc[ct] = (f32x4){0.f, 0.f, 0.f, 0.f};

    #pragma unroll
    for (int kc = 0; kc < KDIM / 32; kc++) {
        short8v bfrag[8];
        #pragma unroll
        for (int ct = 0; ct < 8; ct++)
            bfrag[ct] = *(const short8v*)(Wt + (long)(ct * 16 + lr) * KDIM + kc * 32 + quad * 8);
        #pragma unroll
        for (int ct = 0; ct < 8; ct++)
            acc[ct] = __builtin_amdgcn_mfma_f32_16x16x32_bf16(afrag[kc], bfrag[ct], acc[ct], 0, 0, 0);
    }

    if (EPI == 0) {
        #pragma unroll
        for (int ct = 0; ct < 8; ct++) {
            float bc = Bb ? Bb[ct * 16 + lr] : 0.f;
            #pragma unroll
            for (int r = 0; r < 4; r++) {
                int orow = row0 + quad * 4 + r;
                if (orow < M)
                    C[(long)orow * HID + ct * 16 + lr] = __float2bfloat16(acc[ct][r] + bc);
            }
        }
    } else {
        float part = 0.f;
        #pragma unroll
        for (int ct = 0; ct < 8; ct++) {
            float bc = Bb ? Bb[ct * 16 + lr] : 0.f;
            float qc = qv[ct * 16 + lr];
            #pragma unroll
            for (int r = 0; r < 4; r++) {
                int orow = row0 + quad * 4 + r;
                if (orow < M) part += qc * fast_tanh(acc[ct][r] + bc);
            }
        }
        red[tid] = part;
        __syncthreads();
        for (int s = 128; s > 0; s >>= 1) {
            if (tid < s) red[tid] += red[tid + s];
            __syncthreads();
        }
        if (tid == 0) atomicAdd(score, red[0]);
    }
}

template<int KDIM, int EPI>
__global__ __launch_bounds__(256) void bgemm_kernel(
    const bf16* __restrict__ A, const bf16* __restrict__ Wt, const float* __restrict__ Bb,
    bf16* __restrict__ C, const float* __restrict__ qv, float* __restrict__ score, int M)
{
    __shared__ float red[256];
    bgemm_body<KDIM, EPI>(A, Wt, Bb, C, qv, score, M, blockIdx.x, red);
}

template<int KDIM, int EPI>
__global__ __launch_bounds__(256) void bgemm_pair_kernel(
    const bf16* __restrict__ A0, const bf16* __restrict__ Wt0, const float* __restrict__ Bb0,
    bf16* __restrict__ C0, float* __restrict__ score0, int M0, int NB0,
    const bf16* __restrict__ A1, const bf16* __restrict__ Wt1, const float* __restrict__ Bb1,
    bf16* __restrict__ C1, float* __restrict__ score1, int M1,
    const float* __restrict__ qv)
{
    __shared__ float red[256];
    const int bx = blockIdx.x;
    if (bx < NB0)
        bgemm_body<KDIM, EPI>(A0, Wt0, Bb0, C0, qv, score0, M0, bx, red);
    else
        bgemm_body<KDIM, EPI>(A1, Wt1, Bb1, C1, qv, score1, M1, bx - NB0, red);
}

// ---------------------------------------------------------------------------
// one-time conversions, merged: weights -> bf16 transposed + activations -> bf16
// ---------------------------------------------------------------------------
#define R_WA  (128 * 64)
#define R_PW  (4 * 128 * 128)
#define R_KW  (2 * 128 * 128)
#define NXA (N_AUTHOR * 64)
#define NXP (N_PAPER * HID)
#define CONV_W_TOT (R_WA + R_PW + R_KW)
#define CONV_X_TOT ((NXA + NXP) / 4)

__global__ void conv_all_kernel(const float* __restrict__ Wa,
                                const float* __restrict__ proj_w,
                                const float* __restrict__ klin_w,
                                const float* __restrict__ xa_f,
                                const float* __restrict__ xp_f,
                                bf16* __restrict__ wt_wa,
                                bf16* __restrict__ wt_proj,
                                bf16* __restrict__ wt_klin,
                                bf16* __restrict__ xa,
                                bf16* __restrict__ xp)
{
    int t = blockIdx.x * blockDim.x + threadIdx.x;
    if (t < CONV_W_TOT) {
        int i = t;
        if (i < R_WA) {
            int n = i >> 6, k = i & 63;
            wt_wa[i] = __float2bfloat16(Wa[k * 128 + n]);
        } else if (i < R_WA + R_PW) {
            int j = i - R_WA;
            int m = j >> 14, r = j & 16383;
            int n = r >> 7, k = r & 127;
            wt_proj[j] = __float2bfloat16(proj_w[m * 16384 + k * 128 + n]);
        } else {
            int j = i - R_WA - R_PW;
            int m = j >> 14, r = j & 16383;
            int n = r >> 7, k = r & 127;
            wt_klin[j] = __float2bfloat16(klin_w[m * 16384 + k * 128 + n]);
        }
    } else if (t < CONV_W_TOT + CONV_X_TOT) {
        int i = (t - CONV_W_TOT) * 4;
        if (i < NXA) {
            float4 v = *(const float4*)(xa_f + i);
            xa[i]   = __float2bfloat16(v.x); xa[i+1] = __float2bfloat16(v.y);
            xa[i+2] = __float2bfloat16(v.z); xa[i+3] = __float2bfloat16(v.w);
        } else {
            int j = i - NXA;
            float4 v = *(const float4*)(xp_f + j);
            xp[j]   = __float2bfloat16(v.x); xp[j+1] = __float2bfloat16(v.y);
            xp[j+2] = __float2bfloat16(v.z); xp[j+3] = __float2bfloat16(v.w);
        }
    }
}

// multi-output node attention dots
__global__ void node_att_multi_kernel(const bf16* __restrict__ xh,
    const float* __restrict__ A0, const float* __restrict__ A1,
    const float* __restrict__ A2, const float* __restrict__ A3,
    float* __restrict__ O0, float* __restrict__ O1,
    float* __restrict__ O2, float* __restrict__ O3, int N)
{
    int i = blockIdx.x * blockDim.x + threadIdx.x;
    if (i >= N * HEADS) return;
    int n = i >> 3, h = i & 7;
    const bf16* row = xh + (long)n * HID + h * DIMH;
    float x[DIMH];
    #pragma unroll
    for (int d = 0; d < DIMH; d++) x[d] = __bfloat162float(row[d]);
    if (A0) { float s = 0.f;
        #pragma unroll
        for (int d = 0; d < DIMH; d++) s += x[d] * A0[h*DIMH + d];
        O0[i] = s; }
    if (A1) { float s = 0.f;
        #pragma unroll
        for (int d = 0; d < DIMH; d++) s += x[d] * A1[h*DIMH + d];
        O1[i] = s; }
    if (A2) { float s = 0.f;
        #pragma unroll
        for (int d = 0; d < DIMH; d++) s += x[d] * A2[h*DIMH + d];
        O2[i] = s; }
    if (A3) { float s = 0.f;
        #pragma unroll
        for (int d = 0; d < DIMH; d++) s += x[d] * A3[h*DIMH + d];
        O3[i] = s; }
}

// ---------------- batched CSR build ----------------
#define CNT_OFF1 N_PAPER
#define CNT_OFF2 (N_PAPER + N_AUTHOR)
#define E3 (3 * NEDGE)
#define HIST_T (E3 / 4)          // threads; each does 4 grid-strided edges

// 4 independent atomics per thread -> 4 RMWs in flight (latency hiding)
__global__ void hist3_kernel(const int* __restrict__ d0, const int* __restrict__ d1,
                             const int* __restrict__ d2, int* __restrict__ cnt,
                             unsigned short* __restrict__ rank)
{
    int t = blockIdx.x * blockDim.x + threadIdx.x;
    if (t >= HIST_T) return;
    #pragma unroll
    for (int u = 0; u < 4; u++) {
        int i = t + u * HIST_T;
        int r;
        if (i < NEDGE)            r = atomicAdd(&cnt[d0[i]], 1);
        else if (i < 2*NEDGE)     r = atomicAdd(&cnt[CNT_OFF1 + d1[i - NEDGE]], 1);
        else                      r = atomicAdd(&cnt[CNT_OFF2 + d2[i - 2*NEDGE]], 1);
        rank[i] = (unsigned short)r;
    }
}

__device__ __forceinline__ int job_nd(int j){ return j == 1 ? N_AUTHOR : N_PAPER; }
__device__ __forceinline__ int job_off(int j){ return j == 0 ? 0 : (j == 1 ? CNT_OFF1 : CNT_OFF2); }

__global__ __launch_bounds__(256) void scan_a3_kernel(const int* __restrict__ cnt,
                                                      int* __restrict__ bsum)
{
    int j = blockIdx.y;
    int nd = job_nd(j), off = job_off(j);
    __shared__ int s[256];
    int tid = threadIdx.x;
    int i = blockIdx.x * 256 + tid;
    s[tid] = (i < nd) ? cnt[off + i] : 0;
    __syncthreads();
    for (int st = 128; st > 0; st >>= 1) {
        if (tid < st) s[tid] += s[tid + st];
        __syncthreads();
    }
    if (tid == 0) bsum[j * 256 + blockIdx.x] = s[0];
}

__global__ __launch_bounds__(256) void scan_b3_kernel(int* __restrict__ bsum,
    int* __restrict__ roff0, int* __restrict__ roff1, int* __restrict__ roff2)
{
    int j = blockIdx.x;
    int nd = job_nd(j);
    int nb = (nd + 255) / 256;
    int* roff = j == 0 ? roff0 : (j == 1 ? roff1 : roff2);
    __shared__ int s[256];
    int tid = threadIdx.x;
    int v = (tid < nb) ? bsum[j * 256 + tid] : 0;
    s[tid] = v;
    __syncthreads();
    for (int off = 1; off < 256; off <<= 1) {
        int t = (tid >= off) ? s[tid - off] : 0;
        __syncthreads();
        s[tid] += t;
        __syncthreads();
    }
    if (tid < nb) bsum[j * 256 + tid] = s[tid] - v;
    if (tid == 255) roff[nd] = s[255];
}

__global__ __launch_bounds__(256) void scan_c3_kernel(const int* __restrict__ cnt,
    const int* __restrict__ bsum,
    int* __restrict__ roff0, int* __restrict__ roff1, int* __restrict__ roff2)
{
    int j = blockIdx.y;
    int nd = job_nd(j), off = job_off(j);
    int* roff = j == 0 ? roff0 : (j == 1 ? roff1 : roff2);
    __shared__ int s[256];
    int tid = threadIdx.x;
    int i = blockIdx.x * 256 + tid;
    int v = (i < nd) ? cnt[off + i] : 0;
    s[tid] = v;
    __syncthreads();
    for (int o = 1; o < 256; o <<= 1) {
        int t = (tid >= o) ? s[tid - o] : 0;
        __syncthreads();
        s[tid] += t;
        __syncthreads();
    }
    if (i < nd) roff[i] = bsum[j * 256 + blockIdx.x] + s[tid] - v;
}

// 4 edges per thread, grid-strided; no atomics (rank precomputed)
__global__ void fill3_kernel(
    const int* __restrict__ s0, const int* __restrict__ d0,
    const int* __restrict__ s1, const int* __restrict__ d1,
    const int* __restrict__ s2, const int* __restrict__ d2,
    const int* __restrict__ roff0, const int* __restrict__ roff1, const int* __restrict__ roff2,
    const unsigned short* __restrict__ rank,
    unsigned short* __restrict__ c0, unsigned short* __restrict__ c1, unsigned short* __restrict__ c2)
{
    int t = blockIdx.x * blockDim.x + threadIdx.x;
    if (t >= HIST_T) return;
    #pragma unroll
    for (int u = 0; u < 4; u++) {
        int i = t + u * HIST_T;
        if (i < NEDGE) {
            int d = d0[i];
            c0[roff0[d] + rank[i]] = (unsigned short)s0[i];
        } else if (i < 2*NEDGE) {
            int e = i - NEDGE, d = d1[e];
            c1[roff1[d] + rank[i]] = (unsigned short)s1[e];
        } else {
            int e = i - 2*NEDGE, d = d2[e];
            c2[roff2[d] + rank[i]] = (unsigned short)s2[e];
        }
    }
}

// ---------------------------------------------------------------------------
// Fused paper gather: 16 lanes per dest, lane owns 8 features, 4-deep batch.
// ---------------------------------------------------------------------------
__global__ __launch_bounds__(256) void paper_gather2_kernel(
    const int* __restrict__ roff0, const unsigned short* __restrict__ csrc0,
    const float* __restrict__ as0, const float* __restrict__ ad0,
    const bf16* __restrict__ xha,
    const int* __restrict__ roff2, const unsigned short* __restrict__ csrc2,
    const float* __restrict__ as2, const float* __restrict__ ad2,
    const bf16* __restrict__ xhp,
    bf16* __restrict__ out0, bf16* __restrict__ out2)
{
    int lane = threadIdx.x & 63;
    int li   = lane & 15;
    int sub  = lane >> 4;
    int w = blockIdx.x * 16 + (threadIdx.x >> 6) * 4 + sub;
    if (w >= N_PAPER) return;
    int h = li >> 1;

    int b0 = roff0[w], n0 = roff0[w + 1] - b0;
    int b2 = roff2[w], n2 = roff2[w + 1] - b2;
    float ad0v = ad0[(long)w * 8 + h];
    float ad2v = ad2[(long)w * 8 + h];
    float den0 = 0.f, den2 = 0.f;
    float acc0[8], acc2[8];
    #pragma unroll
    for (int j = 0; j < 8; j++) { acc0[j] = 0.f; acc2[j] = 0.f; }

    int nmax = n0 > n2 ? n0 : n2;
    int c0m = n0 > 0 ? n0 - 1 : 0;
    int c2m = n2 > 0 ? n2 - 1 : 0;
    for (int i = 0; i < nmax; i += 4) {
        int sA[4], sB[4];
        #pragma unroll
        for (int u = 0; u < 4; u++) {
            sA[u] = csrc0[b0 + min(i + u, c0m)];
            sB[u] = csrc2[b2 + min(i + u, c2m)];
        }
        float aA[4], aB[4];
        short8v xA[4], xB[4];
        #pragma unroll
        for (int u = 0; u < 4; u++) {
            aA[u] = as0[(long)sA[u] * 8 + h];
            xA[u] = *(const short8v*)(xha + (long)sA[u] * HID + li * 8);
            aB[u] = as2[(long)sB[u] * 8 + h];
            xB[u] = *(const short8v*)(xhp + (long)sB[u] * HID + li * 8);
        }
        #pragma unroll
        for (int u = 0; u < 4; u++) {
            float a = aA[u] + ad0v;
            a = a >= 0.f ? a : 0.2f * a;
            float wt = __expf(fminf(a, 60.f));
            wt = (i + u < n0) ? wt : 0.f;
            den0 += wt;
            #pragma unroll
            for (int j = 0; j < 8; j++)
                acc0[j] = fmaf(b2f(xA[u][j]), wt, acc0[j]);
            a = aB[u] + ad2v;
            a = a >= 0.f ? a : 0.2f * a;
            wt = __expf(fminf(a, 60.f));
            wt = (i + u < n2) ? wt : 0.f;
            den2 += wt;
            #pragma unroll
            for (int j = 0; j < 8; j++)
                acc2[j] = fmaf(b2f(xB[u][j]), wt, acc2[j]);
        }
    }
    float inv0 = fastrcp(den0 + 1e-16f);
    float inv2 = fastrcp(den2 + 1e-16f);
    short8v o0, o2;
    #pragma unroll
    for (int j = 0; j < 8; j++) {
        o0[j] = f2bs(fmaxf(acc0[j] * inv0, 0.f));
        o2[j] = f2bs(fmaxf(acc2[j] * inv2, 0.f));
    }
    *(short8v*)(out0 + (long)w * HID + li * 8) = o0;
    *(short8v*)(out2 + (long)w * HID + li * 8) = o2;
}

// single gather (author dest, layer 0 only)
__global__ __launch_bounds__(256) void edge_gather_kernel(
    const int* __restrict__ roff, const unsigned short* __restrict__ csrc,
    const float* __restrict__ as_, const float* __restrict__ ad_,
    const bf16* __restrict__ xh, bf16* __restrict__ out, int Ndst)
{
    int lane = threadIdx.x & 63;
    int li   = lane & 15;
    int sub  = lane >> 4;
    int w = blockIdx.x * 16 + (threadIdx.x >> 6) * 4 + sub;
    if (w >= Ndst) return;
    int h = li >> 1;
    int beg = roff[w], n = roff[w + 1] - beg;
    float adv = ad_[(long)w * 8 + h];
    float den = 0.f;
    float acc[8];
    #pragma unroll
    for (int j = 0; j < 8; j++) acc[j] = 0.f;
    int cm = n > 0 ? n - 1 : 0;
    for (int i = 0; i < n; i += 4) {
        int s[4];
        #pragma unroll
        for (int u = 0; u < 4; u++) s[u] = csrc[beg + min(i + u, cm)];
        float av[4]; short8v xv[4];
        #pragma unroll
        for (int u = 0; u < 4; u++) {
            av[u] = as_[(long)s[u] * 8 + h];
            xv[u] = *(const short8v*)(xh + (long)s[u] * HID + li * 8);
        }
        #pragma unroll
        for (int u = 0; u < 4; u++) {
            float a = av[u] + adv;
            a = a >= 0.f ? a : 0.2f * a;
            float wt = __expf(fminf(a, 60.f));
            wt = (i + u < n) ? wt : 0.f;
            den += wt;
            #pragma unroll
            for (int j = 0; j < 8; j++)
                acc[j] = fmaf(b2f(xv[u][j]), wt, acc[j]);
        }
    }
    float inv = fastrcp(den + 1e-16f);
    short8v o;
    #pragma unroll
    for (int j = 0; j < 8; j++) o[j] = f2bs(fmaxf(acc[j] * inv, 0.f));
    *(short8v*)(out + (long)w * HID + li * 8) = o;
}

// semantic combine: bf16 in, bf16 out
__global__ void combine_kernel(const bf16* __restrict__ a0, const bf16* __restrict__ a1,
                               const float* __restrict__ score, bf16* __restrict__ out, int n2)
{
    int i = blockIdx.x * blockDim.x + threadIdx.x;
    if (i >= n2) return;
    float s0 = score[0] * (1.f / N_PAPER);
    float s1 = score[1] * (1.f / N_PAPER);
    float m = fmaxf(s0, s1);
    float e0 = __expf(s0 - m), e1 = __expf(s1 - m);
    float inv = fastrcp(e0 + e1);
    float w0 = e0 * inv, w1 = e1 * inv;
    bf162 v0 = ((const bf162*)a0)[i];
    bf162 v1 = ((const bf162*)a1)[i];
    ((bf162*)out)[i] = mk2(w0 * __bfloat162float(v0.x) + w1 * __bfloat162float(v1.x),
                           w0 * __bfloat162float(v0.y) + w1 * __bfloat162float(v1.y));
}

// final linear fused with last-layer semantic combine
__global__ __launch_bounds__(256) void final_lin_fused_kernel(
    const bf16* __restrict__ a0, const bf16* __restrict__ a1,
    const float* __restrict__ score,
    const float* __restrict__ W, const float* __restrict__ B, float* __restrict__ out)
{
    __shared__ float Ws[HID * NCLS];
    int tid = threadIdx.x;
    for (int i = tid; i < HID * NCLS; i += 256) Ws[i] = W[i];
    __syncthreads();
    float s0 = score[0] * (1.f / N_PAPER);
    float s1 = score[1] * (1.f / N_PAPER);
    float m = fmaxf(s0, s1);
    float e0 = __expf(s0 - m), e1 = __expf(s1 - m);
    float inv = 1.f / (e0 + e1);
    float w0 = e0 * inv, w1 = e1 * inv;
    int i = blockIdx.x * 256 + tid;
    if (i >= N_PAPER * NCLS) return;
    int n = i >> 4, c = i & 15;
    float acc = B[c];
    const bf16* x0 = a0 + (long)n * HID;
    const bf16* x1 = a1 + (long)n * HID;
    #pragma unroll 16
    for (int k = 0; k < HID; k++)
        acc = fmaf(fmaf(w0, __bfloat162float(x0[k]), w1 * __bfloat162float(x1[k])),
                   Ws[k * NCLS + c], acc);
    out[i] = acc;
}

extern "C" void kernel_launch(void* const* d_in, const int* in_sizes, int n_in,
                              void* d_out, int out_size, void* d_ws, size_t ws_size,
                              hipStream_t stream)
{
    const float* x_author = (const float*)d_in[0];
    const float* x_paper  = (const float*)d_in[1];
    const float* Wa       = (const float*)d_in[2];
    const float* proj_w   = (const float*)d_in[3];
    const float* proj_b   = (const float*)d_in[4];
    const float* att_src  = (const float*)d_in[5];
    const float* att_dst  = (const float*)d_in[6];
    const float* klin_w   = (const float*)d_in[7];
    const float* klin_b   = (const float*)d_in[8];
    const float* qv       = (const float*)d_in[9];
    const float* lin_w    = (const float*)d_in[10];
    const float* lin_b    = (const float*)d_in[11];
    const int*  ei_w      = (const int*)d_in[12];
    const int*  ei_wb     = (const int*)d_in[13];
    const int*  ei_c      = (const int*)d_in[14];
    float* out = (float*)d_out;
    (void)ws_size; (void)in_sizes; (void)n_in; (void)out_size;

    char* base = (char*)d_ws;
    size_t off = 0;
    auto alloc = [&](size_t bytes) {
        void* p = base + off;
        off = (off + bytes + 255) & ~(size_t)255;
        return p;
    };
    bf16*  xh_a  = (bf16*) alloc((size_t)N_AUTHOR * HID * 2);
    bf16*  xh_p  = (bf16*) alloc((size_t)N_PAPER  * HID * 2);
    bf16*  buf_a = (bf16*) alloc((size_t)N_AUTHOR * HID * 2);
    bf16*  buf_p = (bf16*) alloc((size_t)N_PAPER  * HID * 2);
    bf16*  agg_p1= (bf16*) alloc((size_t)N_PAPER  * HID * 2);
    bf16*  xa    = (bf16*) alloc((size_t)N_AUTHOR * 64  * 2);
    bf16*  xp    = (bf16*) alloc((size_t)N_PAPER  * HID * 2);
    bf16*  wt_wa   = (bf16*)alloc((size_t)R_WA * 2);
    bf16*  wt_proj = (bf16*)alloc((size_t)R_PW * 2);
    bf16*  wt_klin = (bf16*)alloc((size_t)R_KW * 2);
    float* a_e0s = (float*)alloc((size_t)N_AUTHOR * HEADS * 4);
    float* a_e0d = (float*)alloc((size_t)N_PAPER  * HEADS * 4);
    float* a_e1s = (float*)alloc((size_t)N_PAPER  * HEADS * 4);
    float* a_e1d = (float*)alloc((size_t)N_AUTHOR * HEADS * 4);
    float* a_e2s = (float*)alloc((size_t)N_PAPER  * HEADS * 4);
    float* a_e2d = (float*)alloc((size_t)N_PAPER  * HEADS * 4);
    float* score  = (float*)alloc(64);
    int* roff0 = (int*)alloc((size_t)(N_PAPER  + 1) * 4);
    int* roff1 = (int*)alloc((size_t)(N_AUTHOR + 1) * 4);
    int* roff2 = (int*)alloc((size_t)(N_PAPER  + 1) * 4);
    unsigned short* csrc0 = (unsigned short*)alloc((size_t)NEDGE * 2 + 64);
    unsigned short* csrc1 = (unsigned short*)alloc((size_t)NEDGE * 2 + 64);
    unsigned short* csrc2 = (unsigned short*)alloc((size_t)NEDGE * 2 + 64);
    int* cnt   = (int*)alloc((size_t)(2 * N_PAPER + N_AUTHOR) * 4);
    unsigned short* rank = (unsigned short*)alloc((size_t)E3 * 2);
    int* bsum  = (int*)alloc(3 * 256 * 4);

    const int GA = (N_AUTHOR + 63) / 64;   // 313
    const int GP = (N_PAPER  + 63) / 64;   // 625
    const int NBMAX = (N_PAPER + 255) / 256;   // 157

    // ---- one-time conversions (single launch) ----
    conv_all_kernel<<<(CONV_W_TOT + CONV_X_TOT + 255)/256, 256, 0, stream>>>(
        Wa, proj_w, klin_w, x_author, x_paper,
        wt_wa, wt_proj, wt_klin, xa, xp);

    // ---- batched CSR build (4-edge/thread hist + fill) ----
    hipMemsetAsync(cnt, 0, (size_t)(2 * N_PAPER + N_AUTHOR) * 4, stream);
    hist3_kernel<<<(HIST_T + 255)/256, 256, 0, stream>>>(
        ei_w + NEDGE, ei_wb + NEDGE, ei_c + NEDGE, cnt, rank);
    scan_a3_kernel<<<dim3(NBMAX, 3), 256, 0, stream>>>(cnt, bsum);
    scan_b3_kernel<<<3, 256, 0, stream>>>(bsum, roff0, roff1, roff2);
    scan_c3_kernel<<<dim3(NBMAX, 3), 256, 0, stream>>>(cnt, bsum, roff0, roff1, roff2);
    fill3_kernel<<<(HIST_T + 255)/256, 256, 0, stream>>>(
        ei_w, ei_w + NEDGE, ei_wb, ei_wb + NEDGE, ei_c, ei_c + NEDGE,
        roff0, roff1, roff2, rank, csrc0, csrc1, csrc2);

    // author input projection 64 -> 128 (bf16 out)
    bgemm_kernel<64, 0><<<GA, 256, 0, stream>>>(
        xa, wt_wa, nullptr, buf_a, nullptr, nullptr, N_AUTHOR);

    for (int l = 0; l < 2; l++) {
        const bool last = (l == 1);
        const bf16* cur_a = buf_a;
        const bf16* cur_p = (l == 0) ? xp : buf_p;
        const bf16* pw_a = wt_proj + (size_t)(l*2 + 0) * HID * HID;
        const bf16* pw_p = wt_proj + (size_t)(l*2 + 1) * HID * HID;
        const float* pb_a = proj_b + (size_t)(l*2 + 0) * HID;
        const float* pb_p = proj_b + (size_t)(l*2 + 1) * HID;

        bgemm_pair_kernel<128, 0><<<GA + GP, 256, 0, stream>>>(
            cur_a, pw_a, pb_a, xh_a, nullptr, N_AUTHOR, GA,
            cur_p, pw_p, pb_p, xh_p, nullptr, N_PAPER, nullptr);

        hipMemsetAsync(score, 0, 64, stream);

        const float* as0 = att_src + (size_t)(l*3 + 0) * HID;
        const float* ad0 = att_dst + (size_t)(l*3 + 0) * HID;
        const float* as1 = att_src + (size_t)(l*3 + 1) * HID;
        const float* ad1 = att_dst + (size_t)(l*3 + 1) * HID;
        const float* as2 = att_src + (size_t)(l*3 + 2) * HID;
        const float* ad2 = att_dst + (size_t)(l*3 + 2) * HID;

        node_att_multi_kernel<<<(N_AUTHOR*HEADS + 255)/256, 256, 0, stream>>>(
            xh_a, as0, last ? nullptr : ad1, nullptr, nullptr,
            a_e0s, a_e1d, nullptr, nullptr, N_AUTHOR);
        node_att_multi_kernel<<<(N_PAPER*HEADS + 255)/256, 256, 0, stream>>>(
            xh_p, ad0, last ? nullptr : as1, as2, ad2,
            a_e0d, a_e1s, a_e2s, a_e2d, N_PAPER);

        paper_gather2_kernel<<<(N_PAPER + 15)/16, 256, 0, stream>>>(
            roff0, csrc0, a_e0s, a_e0d, xh_a,
            roff2, csrc2, a_e2s, a_e2d, xh_p,
            buf_p, agg_p1);
        if (!last)
            edge_gather_kernel<<<(N_AUTHOR + 15)/16, 256, 0, stream>>>(
                roff1, csrc1, a_e1s, a_e1d, xh_p, buf_a, N_AUTHOR);

        const bf16* kw = wt_klin + (size_t)l * HID * HID;
        const float* kb = klin_b + (size_t)l * HID;
        const float* qq = qv     + (size_t)l * HID;
        bgemm_pair_kernel<128, 1><<<2 * GP, 256, 0, stream>>>(
            buf_p, kw, kb, (bf16*)nullptr, score + 0, N_PAPER, GP,
            agg_p1, kw, kb, (bf16*)nullptr, score + 1, N_PAPER, qq);

        if (!last)
            combine_kernel<<<(N_PAPER*HID/2 + 255)/256, 256, 0, stream>>>(
                buf_p, agg_p1, score, buf_p, N_PAPER*HID/2);
    }

    final_lin_fused_kernel<<<(N_PAPER*NCLS + 255)/256, 256, 0, stream>>>(
        buf_p, agg_p1, score, lin_w, lin_b, out);
}

// Round 14
// 444.616 us; speedup vs baseline: 1.0236x; 1.0236x over previous
//
#include <hip/hip_runtime.h>
#include <hip/hip_bf16.h>

typedef __hip_bfloat16 bf16;
typedef __hip_bfloat162 bf162;

#define N_AUTHOR 20000
#define N_PAPER  40000
#define NEDGE    400000
#define HID      128
#define HEADS    8
#define DIMH     16
#define NCLS     16

typedef short short4v __attribute__((ext_vector_type(4)));
typedef short short8v __attribute__((ext_vector_type(8)));
typedef float f32x4   __attribute__((ext_vector_type(4)));

__device__ __forceinline__ bf162 mk2(float a, float b){
    bf162 r; r.x = __float2bfloat16(a); r.y = __float2bfloat16(b); return r;
}
__device__ __forceinline__ float b2f(short s){
    return __uint_as_float(((unsigned)(unsigned short)s) << 16);
}
__device__ __forceinline__ short f2bs(float v){
    unsigned u = __float_as_uint(v);
    unsigned r = (u + 0x7FFFu + ((u >> 16) & 1u)) >> 16;
    return (short)r;
}
__device__ __forceinline__ float fastrcp(float x){ return __builtin_amdgcn_rcpf(x); }

__device__ __forceinline__ float fast_tanh(float x){
    x = fminf(fmaxf(x, -15.f), 15.f);
    float e = __expf(2.f * x);
    return 1.f - 2.f * fastrcp(e + 1.f);
}

// ---------------------------------------------------------------------------
// LDS-free bf16 MFMA GEMM body; B-loads hoisted 16 at a time (2 kc rounds).
// A bf16 [M][KDIM]; Wt bf16 TRANSPOSED [128][KDIM].
// ---------------------------------------------------------------------------
template<int KDIM, int EPI>
__device__ __forceinline__ void bgemm_body(
    const bf16* __restrict__ A, const bf16* __restrict__ Wt, const float* __restrict__ Bb,
    bf16* __restrict__ C, const float* __restrict__ qv, float* __restrict__ score,
    int M, int brow, float* red)
{
    const int tid  = threadIdx.x;
    const int lane = tid & 63;
    const int wv   = tid >> 6;
    const int lr   = lane & 15;
    const int quad = lane >> 4;
    const int row0 = brow * 64 + wv * 16;
    const int arow_i = row0 + lr;
    const bool rowok = arow_i < M;
    const bf16* arow = A + (long)arow_i * KDIM;

    short8v afrag[KDIM / 32];
    #pragma unroll
    for (int kc = 0; kc < KDIM / 32; kc++) {
        short8v f = {0,0,0,0,0,0,0,0};
        if (rowok) f = *(const short8v*)(arow + kc * 32 + quad * 8);
        afrag[kc] = f;
    }

    f32x4 acc[8];
    #pragma unroll
    for (int ct = 0; ct < 8; ct++) acc[ct] = (f32x4){0.f, 0.f, 0.f, 0.f};

    #pragma unroll
    for (int k0 = 0; k0 < KDIM / 32; k0 += 2) {
        short8v bf[2][8];
        #pragma unroll
        for (int u = 0; u < 2; u++)
            #pragma unroll
            for (int ct = 0; ct < 8; ct++)
                bf[u][ct] = *(const short8v*)(Wt + (long)(ct * 16 + lr) * KDIM + (k0 + u) * 32 + quad * 8);
        #pragma unroll
        for (int u = 0; u < 2; u++)
            #pragma unroll
            for (int ct = 0; ct < 8; ct++)
                acc[ct] = __builtin_amdgcn_mfma_f32_16x16x32_bf16(afrag[k0 + u], bf[u][ct], acc[ct], 0, 0, 0);
    }

    if (EPI == 0) {
        #pragma unroll
        for (int ct = 0; ct < 8; ct++) {
            float bc = Bb ? Bb[ct * 16 + lr] : 0.f;
            #pragma unroll
            for (int r = 0; r < 4; r++) {
                int orow = row0 + quad * 4 + r;
                if (orow < M)
                    C[(long)orow * HID + ct * 16 + lr] = __float2bfloat16(acc[ct][r] + bc);
            }
        }
    } else {
        float part = 0.f;
        #pragma unroll
        for (int ct = 0; ct < 8; ct++) {
            float bc = Bb ? Bb[ct * 16 + lr] : 0.f;
            float qc = qv[ct * 16 + lr];
            #pragma unroll
            for (int r = 0; r < 4; r++) {
                int orow = row0 + quad * 4 + r;
                if (orow < M) part += qc * fast_tanh(acc[ct][r] + bc);
            }
        }
        red[tid] = part;
        __syncthreads();
        for (int s = 128; s > 0; s >>= 1) {
            if (tid < s) red[tid] += red[tid + s];
            __syncthreads();
        }
        if (tid == 0) atomicAdd(score, red[0]);
    }
}

template<int KDIM, int EPI>
__global__ __launch_bounds__(256) void bgemm_pair_kernel(
    const bf16* __restrict__ A0, const bf16* __restrict__ Wt0, const float* __restrict__ Bb0,
    bf16* __restrict__ C0, float* __restrict__ score0, int M0, int NB0,
    const bf16* __restrict__ A1, const bf16* __restrict__ Wt1, const float* __restrict__ Bb1,
    bf16* __restrict__ C1, float* __restrict__ score1, int M1,
    const float* __restrict__ qv)
{
    __shared__ float red[256];
    const int bx = blockIdx.x;
    if (bx < NB0)
        bgemm_body<KDIM, EPI>(A0, Wt0, Bb0, C0, qv, score0, M0, bx, red);
    else
        bgemm_body<KDIM, EPI>(A1, Wt1, Bb1, C1, qv, score1, M1, bx - NB0, red);
}

// ---------------------------------------------------------------------------
// sizes for conversions / CSR
// ---------------------------------------------------------------------------
#define R_WA  (128 * 64)
#define R_PW  (4 * 128 * 128)
#define R_KW  (2 * 128 * 128)
#define NXA (N_AUTHOR * 64)
#define NXP (N_PAPER * HID)
#define CONV_W_TOT (R_WA + R_PW + R_KW)
#define CONV_X_TOT ((NXA + NXP) / 4)
#define CONV_TOT   (CONV_W_TOT + CONV_X_TOT)

#define CNT_OFF1 N_PAPER
#define CNT_OFF2 (N_PAPER + N_AUTHOR)
#define NDEST    (2 * N_PAPER + N_AUTHOR)
#define CSTR     16                      // counter stride: 1 counter per 64B line
#define E3 (3 * NEDGE)
#define HIST_T (E3 / 4)

// ---------------------------------------------------------------------------
// Fused: hist3 (atomic rank capture, spread counters) + weight/act conversions.
// Independent work; hist blocks first (long pole starts immediately).
// ---------------------------------------------------------------------------
__global__ __launch_bounds__(256) void conv_hist_kernel(
    const int* __restrict__ d0, const int* __restrict__ d1, const int* __restrict__ d2,
    int* __restrict__ cnt, unsigned short* __restrict__ rank, int HB,
    const float* __restrict__ Wa, const float* __restrict__ proj_w,
    const float* __restrict__ klin_w,
    const float* __restrict__ xa_f, const float* __restrict__ xp_f,
    bf16* __restrict__ wt_wa, bf16* __restrict__ wt_proj, bf16* __restrict__ wt_klin,
    bf16* __restrict__ xa, bf16* __restrict__ xp)
{
    int bx = blockIdx.x;
    if (bx < HB) {
        int t = bx * 256 + threadIdx.x;
        if (t >= HIST_T) return;
        #pragma unroll
        for (int u = 0; u < 4; u++) {
            int i = t + u * HIST_T;
            int r;
            if (i < NEDGE)            r = atomicAdd(&cnt[(long)d0[i] * CSTR], 1);
            else if (i < 2*NEDGE)     r = atomicAdd(&cnt[(long)(CNT_OFF1 + d1[i - NEDGE]) * CSTR], 1);
            else                      r = atomicAdd(&cnt[(long)(CNT_OFF2 + d2[i - 2*NEDGE]) * CSTR], 1);
            rank[i] = (unsigned short)r;
        }
        return;
    }
    int t = (bx - HB) * 256 + threadIdx.x;
    if (t < CONV_W_TOT) {
        int i = t;
        if (i < R_WA) {
            int n = i >> 6, k = i & 63;
            wt_wa[i] = __float2bfloat16(Wa[k * 128 + n]);
        } else if (i < R_WA + R_PW) {
            int j = i - R_WA;
            int m = j >> 14, r = j & 16383;
            int n = r >> 7, k = r & 127;
            wt_proj[j] = __float2bfloat16(proj_w[m * 16384 + k * 128 + n]);
        } else {
            int j = i - R_WA - R_PW;
            int m = j >> 14, r = j & 16383;
            int n = r >> 7, k = r & 127;
            wt_klin[j] = __float2bfloat16(klin_w[m * 16384 + k * 128 + n]);
        }
    } else if (t < CONV_TOT) {
        int i = (t - CONV_W_TOT) * 4;
        if (i < NXA) {
            float4 v = *(const float4*)(xa_f + i);
            xa[i]   = __float2bfloat16(v.x); xa[i+1] = __float2bfloat16(v.y);
            xa[i+2] = __float2bfloat16(v.z); xa[i+3] = __float2bfloat16(v.w);
        } else {
            int j = i - NXA;
            float4 v = *(const float4*)(xp_f + j);
            xp[j]   = __float2bfloat16(v.x); xp[j+1] = __float2bfloat16(v.y);
            xp[j+2] = __float2bfloat16(v.z); xp[j+3] = __float2bfloat16(v.w);
        }
    }
}

__device__ __forceinline__ int job_nd(int j){ return j == 1 ? N_AUTHOR : N_PAPER; }
__device__ __forceinline__ int job_off(int j){ return j == 0 ? 0 : (j == 1 ? CNT_OFF1 : CNT_OFF2); }

__global__ __launch_bounds__(256) void scan_a3_kernel(const int* __restrict__ cnt,
                                                      int* __restrict__ bsum)
{
    int j = blockIdx.y;
    int nd = job_nd(j), off = job_off(j);
    __shared__ int s[256];
    int tid = threadIdx.x;
    int i = blockIdx.x * 256 + tid;
    s[tid] = (i < nd) ? cnt[(long)(off + i) * CSTR] : 0;
    __syncthreads();
    for (int st = 128; st > 0; st >>= 1) {
        if (tid < st) s[tid] += s[tid + st];
        __syncthreads();
    }
    if (tid == 0) bsum[j * 256 + blockIdx.x] = s[0];
}

__global__ __launch_bounds__(256) void scan_b3_kernel(int* __restrict__ bsum,
    int* __restrict__ roff0, int* __restrict__ roff1, int* __restrict__ roff2)
{
    int j = blockIdx.x;
    int nd = job_nd(j);
    int nb = (nd + 255) / 256;
    int* roff = j == 0 ? roff0 : (j == 1 ? roff1 : roff2);
    __shared__ int s[256];
    int tid = threadIdx.x;
    int v = (tid < nb) ? bsum[j * 256 + tid] : 0;
    s[tid] = v;
    __syncthreads();
    for (int off = 1; off < 256; off <<= 1) {
        int t = (tid >= off) ? s[tid - off] : 0;
        __syncthreads();
        s[tid] += t;
        __syncthreads();
    }
    if (tid < nb) bsum[j * 256 + tid] = s[tid] - v;
    if (tid == 255) roff[nd] = s[255];
}

__global__ __launch_bounds__(256) void scan_c3_kernel(const int* __restrict__ cnt,
    const int* __restrict__ bsum,
    int* __restrict__ roff0, int* __restrict__ roff1, int* __restrict__ roff2)
{
    int j = blockIdx.y;
    int nd = job_nd(j), off = job_off(j);
    int* roff = j == 0 ? roff0 : (j == 1 ? roff1 : roff2);
    __shared__ int s[256];
    int tid = threadIdx.x;
    int i = blockIdx.x * 256 + tid;
    int v = (i < nd) ? cnt[(long)(off + i) * CSTR] : 0;
    s[tid] = v;
    __syncthreads();
    for (int o = 1; o < 256; o <<= 1) {
        int t = (tid >= o) ? s[tid - o] : 0;
        __syncthreads();
        s[tid] += t;
        __syncthreads();
    }
    if (i < nd) roff[i] = bsum[j * 256 + blockIdx.x] + s[tid] - v;
}

// ---------------------------------------------------------------------------
// Fused: author input projection (bgemm K=64) + CSR fill (no atomics).
// ---------------------------------------------------------------------------
__global__ __launch_bounds__(256) void fill_gemm_kernel(
    const bf16* __restrict__ A, const bf16* __restrict__ Wt, bf16* __restrict__ C,
    int M, int GAb,
    const int* __restrict__ s0, const int* __restrict__ d0,
    const int* __restrict__ s1, const int* __restrict__ d1,
    const int* __restrict__ s2, const int* __restrict__ d2,
    const int* __restrict__ roff0, const int* __restrict__ roff1, const int* __restrict__ roff2,
    const unsigned short* __restrict__ rank,
    unsigned short* __restrict__ c0, unsigned short* __restrict__ c1, unsigned short* __restrict__ c2)
{
    __shared__ float red[256];
    int bx = blockIdx.x;
    if (bx < GAb) {
        bgemm_body<64, 0>(A, Wt, nullptr, C, nullptr, nullptr, M, bx, red);
        return;
    }
    int t = (bx - GAb) * 256 + threadIdx.x;
    if (t >= HIST_T) return;
    #pragma unroll
    for (int u = 0; u < 4; u++) {
        int i = t + u * HIST_T;
        if (i < NEDGE) {
            int d = d0[i];
            c0[roff0[d] + rank[i]] = (unsigned short)s0[i];
        } else if (i < 2*NEDGE) {
            int e = i - NEDGE, d = d1[e];
            c1[roff1[d] + rank[i]] = (unsigned short)s1[e];
        } else {
            int e = i - 2*NEDGE, d = d2[e];
            c2[roff2[d] + rank[i]] = (unsigned short)s2[e];
        }
    }
}

// multi-output node attention dots
__global__ void node_att_multi_kernel(const bf16* __restrict__ xh,
    const float* __restrict__ A0, const float* __restrict__ A1,
    const float* __restrict__ A2, const float* __restrict__ A3,
    float* __restrict__ O0, float* __restrict__ O1,
    float* __restrict__ O2, float* __restrict__ O3, int N)
{
    int i = blockIdx.x * blockDim.x + threadIdx.x;
    if (i >= N * HEADS) return;
    int n = i >> 3, h = i & 7;
    const bf16* row = xh + (long)n * HID + h * DIMH;
    float x[DIMH];
    #pragma unroll
    for (int d = 0; d < DIMH; d++) x[d] = __bfloat162float(row[d]);
    if (A0) { float s = 0.f;
        #pragma unroll
        for (int d = 0; d < DIMH; d++) s += x[d] * A0[h*DIMH + d];
        O0[i] = s; }
    if (A1) { float s = 0.f;
        #pragma unroll
        for (int d = 0; d < DIMH; d++) s += x[d] * A1[h*DIMH + d];
        O1[i] = s; }
    if (A2) { float s = 0.f;
        #pragma unroll
        for (int d = 0; d < DIMH; d++) s += x[d] * A2[h*DIMH + d];
        O2[i] = s; }
    if (A3) { float s = 0.f;
        #pragma unroll
        for (int d = 0; d < DIMH; d++) s += x[d] * A3[h*DIMH + d];
        O3[i] = s; }
}

// ---------------------------------------------------------------------------
// Fused paper gather: 16 lanes per dest, lane owns 8 features, 4-deep batch.
// ---------------------------------------------------------------------------
__global__ __launch_bounds__(256) void paper_gather2_kernel(
    const int* __restrict__ roff0, const unsigned short* __restrict__ csrc0,
    const float* __restrict__ as0, const float* __restrict__ ad0,
    const bf16* __restrict__ xha,
    const int* __restrict__ roff2, const unsigned short* __restrict__ csrc2,
    const float* __restrict__ as2, const float* __restrict__ ad2,
    const bf16* __restrict__ xhp,
    bf16* __restrict__ out0, bf16* __restrict__ out2)
{
    int lane = threadIdx.x & 63;
    int li   = lane & 15;
    int sub  = lane >> 4;
    int w = blockIdx.x * 16 + (threadIdx.x >> 6) * 4 + sub;
    if (w >= N_PAPER) return;
    int h = li >> 1;

    int b0 = roff0[w], n0 = roff0[w + 1] - b0;
    int b2 = roff2[w], n2 = roff2[w + 1] - b2;
    float ad0v = ad0[(long)w * 8 + h];
    float ad2v = ad2[(long)w * 8 + h];
    float den0 = 0.f, den2 = 0.f;
    float acc0[8], acc2[8];
    #pragma unroll
    for (int j = 0; j < 8; j++) { acc0[j] = 0.f; acc2[j] = 0.f; }

    int nmax = n0 > n2 ? n0 : n2;
    int c0m = n0 > 0 ? n0 - 1 : 0;
    int c2m = n2 > 0 ? n2 - 1 : 0;
    for (int i = 0; i < nmax; i += 4) {
        int sA[4], sB[4];
        #pragma unroll
        for (int u = 0; u < 4; u++) {
            sA[u] = csrc0[b0 + min(i + u, c0m)];
            sB[u] = csrc2[b2 + min(i + u, c2m)];
        }
        float aA[4], aB[4];
        short8v xA[4], xB[4];
        #pragma unroll
        for (int u = 0; u < 4; u++) {
            aA[u] = as0[(long)sA[u] * 8 + h];
            xA[u] = *(const short8v*)(xha + (long)sA[u] * HID + li * 8);
            aB[u] = as2[(long)sB[u] * 8 + h];
            xB[u] = *(const short8v*)(xhp + (long)sB[u] * HID + li * 8);
        }
        #pragma unroll
        for (int u = 0; u < 4; u++) {
            float a = aA[u] + ad0v;
            a = a >= 0.f ? a : 0.2f * a;
            float wt = __expf(fminf(a, 60.f));
            wt = (i + u < n0) ? wt : 0.f;
            den0 += wt;
            #pragma unroll
            for (int j = 0; j < 8; j++)
                acc0[j] = fmaf(b2f(xA[u][j]), wt, acc0[j]);
            a = aB[u] + ad2v;
            a = a >= 0.f ? a : 0.2f * a;
            wt = __expf(fminf(a, 60.f));
            wt = (i + u < n2) ? wt : 0.f;
            den2 += wt;
            #pragma unroll
            for (int j = 0; j < 8; j++)
                acc2[j] = fmaf(b2f(xB[u][j]), wt, acc2[j]);
        }
    }
    float inv0 = fastrcp(den0 + 1e-16f);
    float inv2 = fastrcp(den2 + 1e-16f);
    short8v o0, o2;
    #pragma unroll
    for (int j = 0; j < 8; j++) {
        o0[j] = f2bs(fmaxf(acc0[j] * inv0, 0.f));
        o2[j] = f2bs(fmaxf(acc2[j] * inv2, 0.f));
    }
    *(short8v*)(out0 + (long)w * HID + li * 8) = o0;
    *(short8v*)(out2 + (long)w * HID + li * 8) = o2;
}

// single gather (author dest, layer 0 only)
__global__ __launch_bounds__(256) void edge_gather_kernel(
    const int* __restrict__ roff, const unsigned short* __restrict__ csrc,
    const float* __restrict__ as_, const float* __restrict__ ad_,
    const bf16* __restrict__ xh, bf16* __restrict__ out, int Ndst)
{
    int lane = threadIdx.x & 63;
    int li   = lane & 15;
    int sub  = lane >> 4;
    int w = blockIdx.x * 16 + (threadIdx.x >> 6) * 4 + sub;
    if (w >= Ndst) return;
    int h = li >> 1;
    int beg = roff[w], n = roff[w + 1] - beg;
    float adv = ad_[(long)w * 8 + h];
    float den = 0.f;
    float acc[8];
    #pragma unroll
    for (int j = 0; j < 8; j++) acc[j] = 0.f;
    int cm = n > 0 ? n - 1 : 0;
    for (int i = 0; i < n; i += 4) {
        int s[4];
        #pragma unroll
        for (int u = 0; u < 4; u++) s[u] = csrc[beg + min(i + u, cm)];
        float av[4]; short8v xv[4];
        #pragma unroll
        for (int u = 0; u < 4; u++) {
            av[u] = as_[(long)s[u] * 8 + h];
            xv[u] = *(const short8v*)(xh + (long)s[u] * HID + li * 8);
        }
        #pragma unroll
        for (int u = 0; u < 4; u++) {
            float a = av[u] + adv;
            a = a >= 0.f ? a : 0.2f * a;
            float wt = __expf(fminf(a, 60.f));
            wt = (i + u < n) ? wt : 0.f;
            den += wt;
            #pragma unroll
            for (int j = 0; j < 8; j++)
                acc[j] = fmaf(b2f(xv[u][j]), wt, acc[j]);
        }
    }
    float inv = fastrcp(den + 1e-16f);
    short8v o;
    #pragma unroll
    for (int j = 0; j < 8; j++) o[j] = f2bs(fmaxf(acc[j] * inv, 0.f));
    *(short8v*)(out + (long)w * HID + li * 8) = o;
}

// semantic combine: bf16 in, bf16 out
__global__ void combine_kernel(const bf16* __restrict__ a0, const bf16* __restrict__ a1,
                               const float* __restrict__ score, bf16* __restrict__ out, int n2)
{
    int i = blockIdx.x * blockDim.x + threadIdx.x;
    if (i >= n2) return;
    float s0 = score[0] * (1.f / N_PAPER);
    float s1 = score[1] * (1.f / N_PAPER);
    float m = fmaxf(s0, s1);
    float e0 = __expf(s0 - m), e1 = __expf(s1 - m);
    float inv = fastrcp(e0 + e1);
    float w0 = e0 * inv, w1 = e1 * inv;
    bf162 v0 = ((const bf162*)a0)[i];
    bf162 v1 = ((const bf162*)a1)[i];
    ((bf162*)out)[i] = mk2(w0 * __bfloat162float(v0.x) + w1 * __bfloat162float(v1.x),
                           w0 * __bfloat162float(v0.y) + w1 * __bfloat162float(v1.y));
}

// final linear fused with last-layer semantic combine
__global__ __launch_bounds__(256) void final_lin_fused_kernel(
    const bf16* __restrict__ a0, const bf16* __restrict__ a1,
    const float* __restrict__ score,
    const float* __restrict__ W, const float* __restrict__ B, float* __restrict__ out)
{
    __shared__ float Ws[HID * NCLS];
    int tid = threadIdx.x;
    for (int i = tid; i < HID * NCLS; i += 256) Ws[i] = W[i];
    __syncthreads();
    float s0 = score[0] * (1.f / N_PAPER);
    float s1 = score[1] * (1.f / N_PAPER);
    float m = fmaxf(s0, s1);
    float e0 = __expf(s0 - m), e1 = __expf(s1 - m);
    float inv = 1.f / (e0 + e1);
    float w0 = e0 * inv, w1 = e1 * inv;
    int i = blockIdx.x * 256 + tid;
    if (i >= N_PAPER * NCLS) return;
    int n = i >> 4, c = i & 15;
    float acc = B[c];
    const bf16* x0 = a0 + (long)n * HID;
    const bf16* x1 = a1 + (long)n * HID;
    #pragma unroll 16
    for (int k = 0; k < HID; k++)
        acc = fmaf(fmaf(w0, __bfloat162float(x0[k]), w1 * __bfloat162float(x1[k])),
                   Ws[k * NCLS + c], acc);
    out[i] = acc;
}

extern "C" void kernel_launch(void* const* d_in, const int* in_sizes, int n_in,
                              void* d_out, int out_size, void* d_ws, size_t ws_size,
                              hipStream_t stream)
{
    const float* x_author = (const float*)d_in[0];
    const float* x_paper  = (const float*)d_in[1];
    const float* Wa       = (const float*)d_in[2];
    const float* proj_w   = (const float*)d_in[3];
    const float* proj_b   = (const float*)d_in[4];
    const float* att_src  = (const float*)d_in[5];
    const float* att_dst  = (const float*)d_in[6];
    const float* klin_w   = (const float*)d_in[7];
    const float* klin_b   = (const float*)d_in[8];
    const float* qv       = (const float*)d_in[9];
    const float* lin_w    = (const float*)d_in[10];
    const float* lin_b    = (const float*)d_in[11];
    const int*  ei_w      = (const int*)d_in[12];
    const int*  ei_wb     = (const int*)d_in[13];
    const int*  ei_c      = (const int*)d_in[14];
    float* out = (float*)d_out;
    (void)ws_size; (void)in_sizes; (void)n_in; (void)out_size;

    char* base = (char*)d_ws;
    size_t off = 0;
    auto alloc = [&](size_t bytes) {
        void* p = base + off;
        off = (off + bytes + 255) & ~(size_t)255;
        return p;
    };
    bf16*  xh_a  = (bf16*) alloc((size_t)N_AUTHOR * HID * 2);
    bf16*  xh_p  = (bf16*) alloc((size_t)N_PAPER  * HID * 2);
    bf16*  buf_a = (bf16*) alloc((size_t)N_AUTHOR * HID * 2);
    bf16*  buf_p = (bf16*) alloc((size_t)N_PAPER  * HID * 2);
    bf16*  agg_p1= (bf16*) alloc((size_t)N_PAPER  * HID * 2);
    bf16*  xa    = (bf16*) alloc((size_t)N_AUTHOR * 64  * 2);
    bf16*  xp    = (bf16*) alloc((size_t)N_PAPER  * HID * 2);
    bf16*  wt_wa   = (bf16*)alloc((size_t)R_WA * 2);
    bf16*  wt_proj = (bf16*)alloc((size_t)R_PW * 2);
    bf16*  wt_klin = (bf16*)alloc((size_t)R_KW * 2);
    float* a_e0s = (float*)alloc((size_t)N_AUTHOR * HEADS * 4);
    float* a_e0d = (float*)alloc((size_t)N_PAPER  * HEADS * 4);
    float* a_e1s = (float*)alloc((size_t)N_PAPER  * HEADS * 4);
    float* a_e1d = (float*)alloc((size_t)N_AUTHOR * HEADS * 4);
    float* a_e2s = (float*)alloc((size_t)N_PAPER  * HEADS * 4);
    float* a_e2d = (float*)alloc((size_t)N_PAPER  * HEADS * 4);
    float* score  = (float*)alloc(64);
    int* roff0 = (int*)alloc((size_t)(N_PAPER  + 1) * 4);
    int* roff1 = (int*)alloc((size_t)(N_AUTHOR + 1) * 4);
    int* roff2 = (int*)alloc((size_t)(N_PAPER  + 1) * 4);
    unsigned short* csrc0 = (unsigned short*)alloc((size_t)NEDGE * 2 + 64);
    unsigned short* csrc1 = (unsigned short*)alloc((size_t)NEDGE * 2 + 64);
    unsigned short* csrc2 = (unsigned short*)alloc((size_t)NEDGE * 2 + 64);
    int* cnt   = (int*)alloc((size_t)NDEST * CSTR * 4);     // spread: 1 counter / 64B
    unsigned short* rank = (unsigned short*)alloc((size_t)E3 * 2);
    int* bsum  = (int*)alloc(3 * 256 * 4);

    const int GA = (N_AUTHOR + 63) / 64;   // 313
    const int GP = (N_PAPER  + 63) / 64;   // 625
    const int NBMAX = (N_PAPER + 255) / 256;   // 157
    const int HB = (HIST_T + 255) / 256;       // 1172
    const int CONVB = (CONV_TOT + 255) / 256;

    // ---- fused hist + conversions (independent work overlapped) ----
    hipMemsetAsync(cnt, 0, (size_t)NDEST * CSTR * 4, stream);
    conv_hist_kernel<<<HB + CONVB, 256, 0, stream>>>(
        ei_w + NEDGE, ei_wb + NEDGE, ei_c + NEDGE, cnt, rank, HB,
        Wa, proj_w, klin_w, x_author, x_paper,
        wt_wa, wt_proj, wt_klin, xa, xp);
    scan_a3_kernel<<<dim3(NBMAX, 3), 256, 0, stream>>>(cnt, bsum);
    scan_b3_kernel<<<3, 256, 0, stream>>>(bsum, roff0, roff1, roff2);
    scan_c3_kernel<<<dim3(NBMAX, 3), 256, 0, stream>>>(cnt, bsum, roff0, roff1, roff2);
    // ---- fused CSR fill + author input projection ----
    fill_gemm_kernel<<<GA + HB, 256, 0, stream>>>(
        xa, wt_wa, buf_a, N_AUTHOR, GA,
        ei_w, ei_w + NEDGE, ei_wb, ei_wb + NEDGE, ei_c, ei_c + NEDGE,
        roff0, roff1, roff2, rank, csrc0, csrc1, csrc2);

    for (int l = 0; l < 2; l++) {
        const bool last = (l == 1);
        const bf16* cur_a = buf_a;
        const bf16* cur_p = (l == 0) ? xp : buf_p;
        const bf16* pw_a = wt_proj + (size_t)(l*2 + 0) * HID * HID;
        const bf16* pw_p = wt_proj + (size_t)(l*2 + 1) * HID * HID;
        const float* pb_a = proj_b + (size_t)(l*2 + 0) * HID;
        const float* pb_p = proj_b + (size_t)(l*2 + 1) * HID;

        bgemm_pair_kernel<128, 0><<<GA + GP, 256, 0, stream>>>(
            cur_a, pw_a, pb_a, xh_a, nullptr, N_AUTHOR, GA,
            cur_p, pw_p, pb_p, xh_p, nullptr, N_PAPER, nullptr);

        hipMemsetAsync(score, 0, 64, stream);

        const float* as0 = att_src + (size_t)(l*3 + 0) * HID;
        const float* ad0 = att_dst + (size_t)(l*3 + 0) * HID;
        const float* as1 = att_src + (size_t)(l*3 + 1) * HID;
        const float* ad1 = att_dst + (size_t)(l*3 + 1) * HID;
        const float* as2 = att_src + (size_t)(l*3 + 2) * HID;
        const float* ad2 = att_dst + (size_t)(l*3 + 2) * HID;

        node_att_multi_kernel<<<(N_AUTHOR*HEADS + 255)/256, 256, 0, stream>>>(
            xh_a, as0, last ? nullptr : ad1, nullptr, nullptr,
            a_e0s, a_e1d, nullptr, nullptr, N_AUTHOR);
        node_att_multi_kernel<<<(N_PAPER*HEADS + 255)/256, 256, 0, stream>>>(
            xh_p, ad0, last ? nullptr : as1, as2, ad2,
            a_e0d, a_e1s, a_e2s, a_e2d, N_PAPER);

        paper_gather2_kernel<<<(N_PAPER + 15)/16, 256, 0, stream>>>(
            roff0, csrc0, a_e0s, a_e0d, xh_a,
            roff2, csrc2, a_e2s, a_e2d, xh_p,
            buf_p, agg_p1);
        if (!last)
            edge_gather_kernel<<<(N_AUTHOR + 15)/16, 256, 0, stream>>>(
                roff1, csrc1, a_e1s, a_e1d, xh_p, buf_a, N_AUTHOR);

        const bf16* kw = wt_klin + (size_t)l * HID * HID;
        const float* kb = klin_b + (size_t)l * HID;
        const float* qq = qv     + (size_t)l * HID;
        bgemm_pair_kernel<128, 1><<<2 * GP, 256, 0, stream>>>(
            buf_p, kw, kb, (bf16*)nullptr, score + 0, N_PAPER, GP,
            agg_p1, kw, kb, (bf16*)nullptr, score + 1, N_PAPER, qq);

        if (!last)
            combine_kernel<<<(N_PAPER*HID/2 + 255)/256, 256, 0, stream>>>(
                buf_p, agg_p1, score, buf_p, N_PAPER*HID/2);
    }

    final_lin_fused_kernel<<<(N_PAPER*NCLS + 255)/256, 256, 0, stream>>>(
        buf_p, agg_p1, score, lin_w, lin_b, out);
}